// Round 15
// baseline (257.453 us; speedup 1.0000x reference)
//
#include <hip/hip_runtime.h>
#include <math.h>

#define VOCAB 50000
#define DD 200
#define AA 32
#define RR 30000
#define LL 40
#define BB 10000

typedef _Float16 half2_t __attribute__((ext_vector_type(2)));

static __device__ __forceinline__ unsigned short f2h(float f) {
    return __builtin_bit_cast(unsigned short, (_Float16)f);   // RNE
}
static __device__ __forceinline__ float hlo(unsigned int u) {
    return (float)__builtin_bit_cast(_Float16, (unsigned short)(u & 0xFFFFu));
}
static __device__ __forceinline__ float hhi(unsigned int u) {
    return (float)__builtin_bit_cast(_Float16, (unsigned short)(u >> 16));
}
static __device__ __forceinline__ unsigned int pkh(float lo, float hi) {
    return (unsigned int)f2h(lo) | ((unsigned int)f2h(hi) << 16);
}
// packed f16 dot2: acc += a.lo*b.lo + a.hi*b.hi
static __device__ __forceinline__ float dot2(unsigned int a, unsigned int b, float acc) {
#if __has_builtin(__builtin_amdgcn_fdot2)
    return __builtin_amdgcn_fdot2(__builtin_bit_cast(half2_t, a),
                                  __builtin_bit_cast(half2_t, b), acc, false);
#else
    return acc + hlo(a) * hlo(b) + hhi(a) * hhi(b);
#endif
}

// ---------------------------------------------------------------------------
// Kernel 0: prep — emb f32->f16 cvt + WM/WW pair-packing, one launch.
// ---------------------------------------------------------------------------
#define NC4 (VOCAB * DD / 4)     /* 2,500,000 float4 chunks */
#define NWM ((DD / 2) * DD)      /* 20,000 */
#define NWW (AA * (DD / 2))      /* 3,200 */
__global__ __launch_bounds__(256) void prep_kernel(
    const float* __restrict__ emb, const float* __restrict__ WM,
    const float* __restrict__ WW, unsigned short* __restrict__ emb16,
    unsigned int* __restrict__ WMP, unsigned int* __restrict__ WWP)
{
    int i = blockIdx.x * 256 + threadIdx.x;
    if (i < NC4) {
        float4 f = ((const float4*)emb)[i];
        ushort4 u;
        u.x = f2h(f.x); u.y = f2h(f.y); u.z = f2h(f.z); u.w = f2h(f.w);
        ((ushort4*)emb16)[i] = u;
    } else if (i < NC4 + NWM) {
        int k = i - NC4;
        int e2 = k / DD, d = k - e2 * DD;
        WMP[k] = pkh(WM[(2 * e2) * DD + d], WM[(2 * e2 + 1) * DD + d]);
    } else if (i < NC4 + NWM + NWW) {
        int k = i - NC4 - NWM;
        int a = k / (DD / 2), c = k - a * (DD / 2);
        WWP[k] = pkh(WW[a * DD + 2 * c], WW[a * DD + 2 * c + 1]);
    }
}

// ---------------------------------------------------------------------------
// Kernel 0c: EW = emb @ WW^T  ([VOCAB,200]@[200,32] -> [VOCAB,32] f32).
// 32 vocab rows per block staged in LDS (packed f16) + WW^T transposed in
// LDS (wwT[c][a]: lane a reads consecutive -> conflict-free; et row read is
// same-address broadcast). Each thread: 4 (row,aspect) pairs x 100 dot2.
// ---------------------------------------------------------------------------
__global__ __launch_bounds__(256) void ew_gemm_kernel(
    const unsigned short* __restrict__ emb16, const unsigned int* __restrict__ WWP,
    float* __restrict__ EW)
{
    __shared__ unsigned int et[32][DD / 2];    // 12.8 KB
    __shared__ unsigned int wwT[DD / 2][AA];   // 12.8 KB
    const int r0 = blockIdx.x * 32;
    const int tid = threadIdx.x;

    for (int i = tid; i < AA * (DD / 2); i += 256) {   // transpose WWP
        int a = i / (DD / 2), c = i - a * (DD / 2);
        wwT[c][a] = WWP[i];
    }
    for (int i = tid; i < 32 * 25; i += 256) {         // stage 32 rows (uint4)
        int rl = i / 25, c4 = i - rl * 25;
        int r = r0 + rl;
        ((uint4*)et[rl])[c4] = (r < VOCAB)
            ? ((const uint4*)(emb16 + (size_t)r * DD))[c4]
            : make_uint4(0u, 0u, 0u, 0u);
    }
    __syncthreads();

    const int a = tid & 31, rg = tid >> 5;
    #pragma unroll
    for (int k = 0; k < 4; ++k) {
        int rl = rg + 8 * k;
        float acc = 0.f;
        #pragma unroll 4
        for (int c = 0; c < DD / 2; ++c)
            acc = dot2(et[rl][c], wwT[c][a], acc);
        int r = r0 + rl;
        if (r < VOCAB) EW[(size_t)r * AA + a] = acc;
    }
}

// ---------------------------------------------------------------------------
// Kernel 1: V = Y @ W_M  with f16 dot2. Y staged as packed f16 in LDS
// (cvt on the fly). Output packed f16 pairs V16[r][i] = (d=2i, d=2i+1).
// ---------------------------------------------------------------------------
__global__ __launch_bounds__(256) void v_gemm_kernel(
    const float* __restrict__ Y, const unsigned int* __restrict__ WMP,
    unsigned int* __restrict__ V16)
{
    __shared__ unsigned int yt[32 * (DD / 2)];   // 12.8 KB packed f16
    const int r0 = blockIdx.x * 32;
    const int tid = threadIdx.x;

    for (int i = tid; i < 32 * 50; i += 256) {   // 50 float4 chunks per row
        int j = i / 50, c = i - 50 * j;
        int r = r0 + j;
        float4 f = (r < RR) ? ((const float4*)(Y + (size_t)r * DD))[c]
                            : make_float4(0.f, 0.f, 0.f, 0.f);
        uint2 u = make_uint2(pkh(f.x, f.y), pkh(f.z, f.w));
        ((uint2*)yt)[i] = u;
    }
    __syncthreads();

    if (tid < DD) {
        float acc[32];
        #pragma unroll
        for (int j = 0; j < 32; ++j) acc[j] = 0.f;
        for (int e2 = 0; e2 < DD / 2; e2 += 2) {
            unsigned int w0 = WMP[e2 * DD + tid];        // coalesced
            unsigned int w1 = WMP[(e2 + 1) * DD + tid];
            #pragma unroll
            for (int j = 0; j < 32; ++j) {
                uint2 y2 = *(const uint2*)(yt + j * (DD / 2) + e2); // broadcast b64
                acc[j] = dot2(y2.x, w0, acc[j]);
                acc[j] = dot2(y2.y, w1, acc[j]);
            }
        }
        #pragma unroll
        for (int j = 0; j < 32; ++j) {
            float partner = __shfl_xor(acc[j], 1);
            int r = r0 + j;
            if (r < RR && (tid & 1) == 0)
                V16[(size_t)r * (DD / 2) + (tid >> 1)] =
                    pkh(acc[j], partner);
        }
    }
}

// ---------------------------------------------------------------------------
// Kernel 2: per-review attention -> p_t [R, A].
// R11 inner loop (f32 z... now wgt only; pk_fma retry regressed twice) with
// the z-pipeline DELETED algebraically: p_t = sum_l wgt_l*EW[w_l]/sum wgt + b
// (EW = emb @ WW^T precomputed). Per-iter: dx dot2s + butterfly + exp +
// ONE fma per lane into a 32-aspect accumulator (idle s>=25 lanes now work).
// No zss round-trip, no normalize/pack, no projection phase.
// ---------------------------------------------------------------------------
__global__ __launch_bounds__(256, 8) void attn_kernel(
    const int* __restrict__ hist, const unsigned short* __restrict__ emb16,
    const unsigned int* __restrict__ V16, const float* __restrict__ EW,
    const float* __restrict__ bW, float* __restrict__ PT)
{
    __shared__ __align__(16) unsigned short ew[LL * DD];  // 16000 B (f16)
    __shared__ __align__(16) unsigned int vp[DD / 2];     // 400 B packed f16
    __shared__ float accs[4][AA];                         // 512 B
    __shared__ float sws[4];

    const int r = blockIdx.x;
    const int tid = threadIdx.x;
    const int* hrow = hist + r * LL;

    // ---- staging: all loads issued up-front (R11-proven) ------------------
    const int i0 = tid, i1 = tid + 256, i2 = tid + 512, i3 = tid + 768;
    const int l0 = i0 / 25, c0 = i0 - 25 * l0;
    const int l1 = i1 / 25, c1 = i1 - 25 * l1;
    const int l2 = i2 / 25, c2 = i2 - 25 * l2;
    const int l3 = i3 / 25, c3 = i3 - 25 * l3;
    const bool has3 = (i3 < LL * 25);

    int w0 = hrow[l0];
    int w1 = hrow[l1];
    int w2 = hrow[l2];
    int w3 = has3 ? hrow[l3] : 0;

    uint4 q0 = ((const uint4*)(emb16 + (size_t)w0 * DD))[c0];
    uint4 q1 = ((const uint4*)(emb16 + (size_t)w1 * DD))[c1];
    uint4 q2 = ((const uint4*)(emb16 + (size_t)w2 * DD))[c2];
    uint4 q3 = has3 ? ((const uint4*)(emb16 + (size_t)w3 * DD))[c3]
                    : make_uint4(0u, 0u, 0u, 0u);
    uint4 vv = make_uint4(0u, 0u, 0u, 0u);
    if (tid < 25) vv = ((const uint4*)(V16 + (size_t)r * (DD / 2)))[tid];

    ((uint4*)ew)[i0] = q0;
    ((uint4*)ew)[i1] = q1;
    ((uint4*)ew)[i2] = q2;
    if (has3) ((uint4*)ew)[i3] = q3;
    if (tid < 25) ((uint4*)vp)[tid] = vv;
    __syncthreads();

    const int wave = tid >> 6, lane = tid & 63;
    const int half = lane >> 5, s = lane & 31;
    const bool act = (s < 25);

    // hoist this lane's v chunk (dims 8s..8s+7) into registers
    uint4 vq = act ? ((const uint4*)vp)[s] : make_uint4(0u, 0u, 0u, 0u);
    // hist row in registers for word-index shuffles
    int h = (lane < LL) ? hrow[lane] : 0;

    // fused dx -> wgt -> p_t accumulate over this wave's 10 words
    float pa = 0.f;     // lane s accumulates aspect s (this half's words)
    float sw = 0.f;
    #pragma unroll 1
    for (int j = 0; j < 5; ++j) {
        const int l = wave * 10 + 2 * j + half;
        float p = 0.f;
        if (act) {
            uint4 eq = *(const uint4*)(ew + l * DD + s * 8);
            p = dot2(eq.x, vq.x, p);
            p = dot2(eq.y, vq.y, p);
            p = dot2(eq.z, vq.z, p);
            p = dot2(eq.w, vq.w, p);
        }
        #pragma unroll
        for (int off = 16; off; off >>= 1) p += __shfl_xor(p, off);
        float wgt = __expf(p - 8.0f);   // shift-invariant unnormalized weight
        sw += wgt;
        int wi = __shfl(h, l);          // this half's word index
        pa += wgt * EW[(size_t)wi * AA + s];   // L2-resident 128B row
    }

    // combine the two halves, then the four waves
    pa += __shfl_xor(pa, 32);
    float swt = sw + __shfl_xor(sw, 32);
    if (half == 0) accs[wave][s] = pa;
    if (lane == 0) sws[wave] = swt;
    __syncthreads();

    if (tid < AA) {
        float tot = sws[0] + sws[1] + sws[2] + sws[3];
        float t = accs[0][tid] + accs[1][tid] + accs[2][tid] + accs[3][tid];
        PT[r * AA + tid] = t / tot + bW[tid];
    }
}

// ---------------------------------------------------------------------------
// Kernel 3: both sparse [B,R] @ p_t [R,A] in one launch.
// 32 lanes per GROUP OF 4 nnz: vectorized int4/float4 idx/val loads,
// 4 coalesced atomics per lane (R12 form; CSR alternative measured slower).
// ---------------------------------------------------------------------------
__global__ __launch_bounds__(256) void spmm_kernel(
    const int* __restrict__ uidx, const float* __restrict__ uval,
    const int* __restrict__ iidx, const float* __restrict__ ival,
    const float* __restrict__ PT, float* __restrict__ out, int nnz)
{
    int g = blockIdx.x * 256 + threadIdx.x;
    int grp = g >> 5;
    int a = g & 31;
    const int gpm = (nnz + 3) >> 2;       // 4-nnz groups per matrix
    const int* idx = uidx;
    const float* val = uval;
    float* o = out;
    if (grp >= gpm) {                     // second matrix
        grp -= gpm;
        if (grp >= gpm) return;
        idx = iidx; val = ival; o += BB * AA;
    }
    const int n0 = grp * 4;

    if (((nnz & 3) == 0) && (n0 + 4 <= nnz)) {
        int4   rows = *(const int4*)(idx + n0);
        int4   cols = *(const int4*)(idx + nnz + n0);
        float4 ws   = *(const float4*)(val + n0);
        atomicAdd(&o[rows.x * AA + a], ws.x * PT[cols.x * AA + a]);
        atomicAdd(&o[rows.y * AA + a], ws.y * PT[cols.y * AA + a]);
        atomicAdd(&o[rows.z * AA + a], ws.z * PT[cols.z * AA + a]);
        atomicAdd(&o[rows.w * AA + a], ws.w * PT[cols.w * AA + a]);
    } else {
        for (int k = 0; k < 4; ++k) {
            int n = n0 + k;
            if (n >= nnz) break;
            int row = idx[n];
            int col = idx[nnz + n];
            float w = val[n];
            atomicAdd(&o[row * AA + a], w * PT[col * AA + a]);
        }
    }
}

extern "C" void kernel_launch(void* const* d_in, const int* in_sizes, int n_in,
                              void* d_out, int out_size, void* d_ws, size_t ws_size,
                              hipStream_t stream) {
    const int*   hist = (const int*)d_in[0];
    const float* ypos = (const float*)d_in[1];
    const int*   uidx = (const int*)d_in[3];
    const float* uval = (const float*)d_in[4];
    const int*   iidx = (const int*)d_in[5];
    const float* ival = (const float*)d_in[6];
    const float* emb  = (const float*)d_in[8];
    const float* WM   = (const float*)d_in[9];
    const float* WW   = (const float*)d_in[10];
    const float* bW   = (const float*)d_in[11];

    unsigned short* emb16 = (unsigned short*)d_ws;                   // 20 MB
    unsigned int* WMP = (unsigned int*)(emb16 + (size_t)VOCAB * DD); // 80 KB
    unsigned int* WWP = WMP + NWM;                                   // 12.8 KB
    unsigned int* V16 = WWP + NWW;                                   // 12 MB
    float* PT = (float*)(V16 + (size_t)RR * (DD / 2));               // 3.84 MB
    float* EW = PT + (size_t)RR * AA;                                // 6.4 MB
    float* out = (float*)d_out;                                      // [2, B, A]

    const int nnz = in_sizes[4];

    hipMemsetAsync(d_out, 0, (size_t)out_size * sizeof(float), stream);

    prep_kernel<<<(NC4 + NWM + NWW + 255) / 256, 256, 0, stream>>>(
        emb, WM, WW, emb16, WMP, WWP);
    ew_gemm_kernel<<<(VOCAB + 31) / 32, 256, 0, stream>>>(emb16, WWP, EW);
    v_gemm_kernel<<<(RR + 31) / 32, 256, 0, stream>>>(ypos, WMP, V16);
    attn_kernel<<<RR, 256, 0, stream>>>(hist, emb16, V16, EW, bW, PT);

    const int gpm = (nnz + 3) >> 2;
    const int spmm_blocks = (2 * gpm * 32 + 255) / 256;
    spmm_kernel<<<spmm_blocks, 256, 0, stream>>>(uidx, uval, iidx, ival, PT, out, nnz);
}

// Round 16
// 250.681 us; speedup vs baseline: 1.0270x; 1.0270x over previous
//
#include <hip/hip_runtime.h>
#include <math.h>

#define VOCAB 50000
#define DD 200
#define AA 32
#define RR 30000
#define LL 40
#define BB 10000

typedef _Float16 half2_t __attribute__((ext_vector_type(2)));

static __device__ __forceinline__ unsigned short f2h(float f) {
    return __builtin_bit_cast(unsigned short, (_Float16)f);   // RNE
}
static __device__ __forceinline__ float hlo(unsigned int u) {
    return (float)__builtin_bit_cast(_Float16, (unsigned short)(u & 0xFFFFu));
}
static __device__ __forceinline__ float hhi(unsigned int u) {
    return (float)__builtin_bit_cast(_Float16, (unsigned short)(u >> 16));
}
static __device__ __forceinline__ unsigned int pkh(float lo, float hi) {
    return (unsigned int)f2h(lo) | ((unsigned int)f2h(hi) << 16);
}
// packed f16 dot2: acc += a.lo*b.lo + a.hi*b.hi
static __device__ __forceinline__ float dot2(unsigned int a, unsigned int b, float acc) {
#if __has_builtin(__builtin_amdgcn_fdot2)
    return __builtin_amdgcn_fdot2(__builtin_bit_cast(half2_t, a),
                                  __builtin_bit_cast(half2_t, b), acc, false);
#else
    return acc + hlo(a) * hlo(b) + hhi(a) * hhi(b);
#endif
}

// ---------------------------------------------------------------------------
// Kernel 0: prep — emb f32->f16 cvt + WM/WW pair-packing, one launch.
// ---------------------------------------------------------------------------
#define NC4 (VOCAB * DD / 4)     /* 2,500,000 float4 chunks */
#define NWM ((DD / 2) * DD)      /* 20,000 */
#define NWW (AA * (DD / 2))      /* 3,200 */
__global__ __launch_bounds__(256) void prep_kernel(
    const float* __restrict__ emb, const float* __restrict__ WM,
    const float* __restrict__ WW, unsigned short* __restrict__ emb16,
    unsigned int* __restrict__ WMP, unsigned int* __restrict__ WWP)
{
    int i = blockIdx.x * 256 + threadIdx.x;
    if (i < NC4) {
        float4 f = ((const float4*)emb)[i];
        ushort4 u;
        u.x = f2h(f.x); u.y = f2h(f.y); u.z = f2h(f.z); u.w = f2h(f.w);
        ((ushort4*)emb16)[i] = u;
    } else if (i < NC4 + NWM) {
        int k = i - NC4;
        int e2 = k / DD, d = k - e2 * DD;
        WMP[k] = pkh(WM[(2 * e2) * DD + d], WM[(2 * e2 + 1) * DD + d]);
    } else if (i < NC4 + NWM + NWW) {
        int k = i - NC4 - NWM;
        int a = k / (DD / 2), c = k - a * (DD / 2);
        WWP[k] = pkh(WW[a * DD + 2 * c], WW[a * DD + 2 * c + 1]);
    }
}

// ---------------------------------------------------------------------------
// Kernel 0c: EW = emb @ WW^T  ([VOCAB,200]@[200,32] -> [VOCAB,32] f32).
// No LDS transpose (R15's wwT had 32-way write conflicts): lane a reads its
// own WWP row as uint4 from global (12.8 KB, L1/L2-resident); 32 emb rows
// staged in LDS, read as same-address broadcast. 4 rows per thread.
// unroll 1: single live uint4 set per iter (spill discipline R6-R9).
// ---------------------------------------------------------------------------
__global__ __launch_bounds__(256) void ew_gemm_kernel(
    const unsigned short* __restrict__ emb16, const unsigned int* __restrict__ WWP,
    float* __restrict__ EW)
{
    __shared__ unsigned int et[32][DD / 2];    // 12.8 KB
    const int r0 = blockIdx.x * 32;
    const int tid = threadIdx.x;

    for (int i = tid; i < 32 * 25; i += 256) {         // stage 32 rows (uint4)
        int rl = i / 25, c4 = i - rl * 25;
        int r = r0 + rl;
        ((uint4*)et[rl])[c4] = (r < VOCAB)
            ? ((const uint4*)(emb16 + (size_t)r * DD))[c4]
            : make_uint4(0u, 0u, 0u, 0u);
    }
    __syncthreads();

    const int a = tid & 31, rg = tid >> 5;   // aspect, row-group (0..7)
    const uint4* wp = (const uint4*)(WWP + a * (DD / 2));
    float acc0 = 0.f, acc1 = 0.f, acc2 = 0.f, acc3 = 0.f;
    #pragma unroll 1
    for (int cc = 0; cc < 25; ++cc) {
        uint4 wq = wp[cc];                              // L1-resident
        uint4 e0 = ((const uint4*)et[rg])[cc];          // LDS broadcast
        uint4 e1 = ((const uint4*)et[rg + 8])[cc];
        uint4 e2 = ((const uint4*)et[rg + 16])[cc];
        uint4 e3 = ((const uint4*)et[rg + 24])[cc];
        acc0 = dot2(e0.x, wq.x, acc0); acc0 = dot2(e0.y, wq.y, acc0);
        acc0 = dot2(e0.z, wq.z, acc0); acc0 = dot2(e0.w, wq.w, acc0);
        acc1 = dot2(e1.x, wq.x, acc1); acc1 = dot2(e1.y, wq.y, acc1);
        acc1 = dot2(e1.z, wq.z, acc1); acc1 = dot2(e1.w, wq.w, acc1);
        acc2 = dot2(e2.x, wq.x, acc2); acc2 = dot2(e2.y, wq.y, acc2);
        acc2 = dot2(e2.z, wq.z, acc2); acc2 = dot2(e2.w, wq.w, acc2);
        acc3 = dot2(e3.x, wq.x, acc3); acc3 = dot2(e3.y, wq.y, acc3);
        acc3 = dot2(e3.z, wq.z, acc3); acc3 = dot2(e3.w, wq.w, acc3);
    }
    if (r0 + rg      < VOCAB) EW[(size_t)(r0 + rg)      * AA + a] = acc0;
    if (r0 + rg + 8  < VOCAB) EW[(size_t)(r0 + rg + 8)  * AA + a] = acc1;
    if (r0 + rg + 16 < VOCAB) EW[(size_t)(r0 + rg + 16) * AA + a] = acc2;
    if (r0 + rg + 24 < VOCAB) EW[(size_t)(r0 + rg + 24) * AA + a] = acc3;
}

// ---------------------------------------------------------------------------
// Kernel 1: V = Y @ W_M  with f16 dot2. Y staged as packed f16 in LDS
// (cvt on the fly). Output packed f16 pairs V16[r][i] = (d=2i, d=2i+1).
// ---------------------------------------------------------------------------
__global__ __launch_bounds__(256) void v_gemm_kernel(
    const float* __restrict__ Y, const unsigned int* __restrict__ WMP,
    unsigned int* __restrict__ V16)
{
    __shared__ unsigned int yt[32 * (DD / 2)];   // 12.8 KB packed f16
    const int r0 = blockIdx.x * 32;
    const int tid = threadIdx.x;

    for (int i = tid; i < 32 * 50; i += 256) {   // 50 float4 chunks per row
        int j = i / 50, c = i - 50 * j;
        int r = r0 + j;
        float4 f = (r < RR) ? ((const float4*)(Y + (size_t)r * DD))[c]
                            : make_float4(0.f, 0.f, 0.f, 0.f);
        uint2 u = make_uint2(pkh(f.x, f.y), pkh(f.z, f.w));
        ((uint2*)yt)[i] = u;
    }
    __syncthreads();

    if (tid < DD) {
        float acc[32];
        #pragma unroll
        for (int j = 0; j < 32; ++j) acc[j] = 0.f;
        for (int e2 = 0; e2 < DD / 2; e2 += 2) {
            unsigned int w0 = WMP[e2 * DD + tid];        // coalesced
            unsigned int w1 = WMP[(e2 + 1) * DD + tid];
            #pragma unroll
            for (int j = 0; j < 32; ++j) {
                uint2 y2 = *(const uint2*)(yt + j * (DD / 2) + e2); // broadcast b64
                acc[j] = dot2(y2.x, w0, acc[j]);
                acc[j] = dot2(y2.y, w1, acc[j]);
            }
        }
        #pragma unroll
        for (int j = 0; j < 32; ++j) {
            float partner = __shfl_xor(acc[j], 1);
            int r = r0 + j;
            if (r < RR && (tid & 1) == 0)
                V16[(size_t)r * (DD / 2) + (tid >> 1)] =
                    pkh(acc[j], partner);
        }
    }
}

// ---------------------------------------------------------------------------
// Kernel 2: per-review attention -> p_t [R, A].
// EW-algebraic form (R15) with the EW gather moved OFF the critical path:
// the 40 needed EW rows (5 KB) are pre-staged into LDS during the e_w
// gather phase (coalesced, latency hidden). Inner loop: ds_read(eq) +
// 4 dot2 + butterfly + exp + 1 LDS read + 1 fma. ews read is 2-way
// bank-aliased (free). LDS ~22 KB -> 7 blocks/CU (same as R11).
// ---------------------------------------------------------------------------
__global__ __launch_bounds__(256, 8) void attn_kernel(
    const int* __restrict__ hist, const unsigned short* __restrict__ emb16,
    const unsigned int* __restrict__ V16, const float* __restrict__ EW,
    const float* __restrict__ bW, float* __restrict__ PT)
{
    __shared__ __align__(16) unsigned short ew[LL * DD];  // 16000 B (f16)
    __shared__ __align__(16) unsigned int vp[DD / 2];     // 400 B packed f16
    __shared__ float ews[LL * AA];                        // 5120 B
    __shared__ float accs[4][AA];                         // 512 B
    __shared__ float sws[4];

    const int r = blockIdx.x;
    const int tid = threadIdx.x;
    const int* hrow = hist + r * LL;

    // ---- staging: all loads issued up-front (R11-proven) ------------------
    const int i0 = tid, i1 = tid + 256, i2 = tid + 512, i3 = tid + 768;
    const int l0 = i0 / 25, c0 = i0 - 25 * l0;
    const int l1 = i1 / 25, c1 = i1 - 25 * l1;
    const int l2 = i2 / 25, c2 = i2 - 25 * l2;
    const int l3 = i3 / 25, c3 = i3 - 25 * l3;
    const bool has3 = (i3 < LL * 25);

    int w0 = hrow[l0];
    int w1 = hrow[l1];
    int w2 = hrow[l2];
    int w3 = has3 ? hrow[l3] : 0;

    uint4 q0 = ((const uint4*)(emb16 + (size_t)w0 * DD))[c0];
    uint4 q1 = ((const uint4*)(emb16 + (size_t)w1 * DD))[c1];
    uint4 q2 = ((const uint4*)(emb16 + (size_t)w2 * DD))[c2];
    uint4 q3 = has3 ? ((const uint4*)(emb16 + (size_t)w3 * DD))[c3]
                    : make_uint4(0u, 0u, 0u, 0u);
    uint4 vv = make_uint4(0u, 0u, 0u, 0u);
    if (tid < 25) vv = ((const uint4*)(V16 + (size_t)r * (DD / 2)))[tid];

    // EW rows for the 40 words: 1280 floats, 5 per thread, coalesced per row
    float g0, g1, g2, g3, g4;
    {
        int ia = tid, ib = tid + 256, ic = tid + 512, id = tid + 768, ie = tid + 1024;
        g0 = EW[(size_t)hrow[ia >> 5] * AA + (ia & 31)];
        g1 = EW[(size_t)hrow[ib >> 5] * AA + (ib & 31)];
        g2 = EW[(size_t)hrow[ic >> 5] * AA + (ic & 31)];
        g3 = EW[(size_t)hrow[id >> 5] * AA + (id & 31)];
        g4 = EW[(size_t)hrow[ie >> 5] * AA + (ie & 31)];
    }

    ((uint4*)ew)[i0] = q0;
    ((uint4*)ew)[i1] = q1;
    ((uint4*)ew)[i2] = q2;
    if (has3) ((uint4*)ew)[i3] = q3;
    if (tid < 25) ((uint4*)vp)[tid] = vv;
    ews[tid]        = g0;
    ews[tid + 256]  = g1;
    ews[tid + 512]  = g2;
    ews[tid + 768]  = g3;
    ews[tid + 1024] = g4;
    __syncthreads();

    const int wave = tid >> 6, lane = tid & 63;
    const int half = lane >> 5, s = lane & 31;
    const bool act = (s < 25);

    // hoist this lane's v chunk (dims 8s..8s+7) into registers
    uint4 vq = act ? ((const uint4*)vp)[s] : make_uint4(0u, 0u, 0u, 0u);

    // fused dx -> wgt -> p_t accumulate over this wave's 10 words
    float pa = 0.f;     // lane s accumulates aspect s (this half's words)
    float sw = 0.f;
    #pragma unroll 1
    for (int j = 0; j < 5; ++j) {
        const int l = wave * 10 + 2 * j + half;
        float p = 0.f;
        if (act) {
            uint4 eq = *(const uint4*)(ew + l * DD + s * 8);
            p = dot2(eq.x, vq.x, p);
            p = dot2(eq.y, vq.y, p);
            p = dot2(eq.z, vq.z, p);
            p = dot2(eq.w, vq.w, p);
        }
        #pragma unroll
        for (int off = 16; off; off >>= 1) p += __shfl_xor(p, off);
        float wgt = __expf(p - 8.0f);   // shift-invariant unnormalized weight
        sw += wgt;
        pa += wgt * ews[l * AA + s];    // LDS, 2-way aliased (free)
    }

    // combine the two halves, then the four waves
    pa += __shfl_xor(pa, 32);
    float swt = sw + __shfl_xor(sw, 32);
    if (half == 0) accs[wave][s] = pa;
    if (lane == 0) sws[wave] = swt;
    __syncthreads();

    if (tid < AA) {
        float tot = sws[0] + sws[1] + sws[2] + sws[3];
        float t = accs[0][tid] + accs[1][tid] + accs[2][tid] + accs[3][tid];
        PT[r * AA + tid] = t / tot + bW[tid];
    }
}

// ---------------------------------------------------------------------------
// Kernel 3: both sparse [B,R] @ p_t [R,A] in one launch.
// 32 lanes per GROUP OF 4 nnz: vectorized int4/float4 idx/val loads,
// 4 coalesced atomics per lane (R12 form; CSR alternative measured slower).
// ---------------------------------------------------------------------------
__global__ __launch_bounds__(256) void spmm_kernel(
    const int* __restrict__ uidx, const float* __restrict__ uval,
    const int* __restrict__ iidx, const float* __restrict__ ival,
    const float* __restrict__ PT, float* __restrict__ out, int nnz)
{
    int g = blockIdx.x * 256 + threadIdx.x;
    int grp = g >> 5;
    int a = g & 31;
    const int gpm = (nnz + 3) >> 2;       // 4-nnz groups per matrix
    const int* idx = uidx;
    const float* val = uval;
    float* o = out;
    if (grp >= gpm) {                     // second matrix
        grp -= gpm;
        if (grp >= gpm) return;
        idx = iidx; val = ival; o += BB * AA;
    }
    const int n0 = grp * 4;

    if (((nnz & 3) == 0) && (n0 + 4 <= nnz)) {
        int4   rows = *(const int4*)(idx + n0);
        int4   cols = *(const int4*)(idx + nnz + n0);
        float4 ws   = *(const float4*)(val + n0);
        atomicAdd(&o[rows.x * AA + a], ws.x * PT[cols.x * AA + a]);
        atomicAdd(&o[rows.y * AA + a], ws.y * PT[cols.y * AA + a]);
        atomicAdd(&o[rows.z * AA + a], ws.z * PT[cols.z * AA + a]);
        atomicAdd(&o[rows.w * AA + a], ws.w * PT[cols.w * AA + a]);
    } else {
        for (int k = 0; k < 4; ++k) {
            int n = n0 + k;
            if (n >= nnz) break;
            int row = idx[n];
            int col = idx[nnz + n];
            float w = val[n];
            atomicAdd(&o[row * AA + a], w * PT[col * AA + a]);
        }
    }
}

extern "C" void kernel_launch(void* const* d_in, const int* in_sizes, int n_in,
                              void* d_out, int out_size, void* d_ws, size_t ws_size,
                              hipStream_t stream) {
    const int*   hist = (const int*)d_in[0];
    const float* ypos = (const float*)d_in[1];
    const int*   uidx = (const int*)d_in[3];
    const float* uval = (const float*)d_in[4];
    const int*   iidx = (const int*)d_in[5];
    const float* ival = (const float*)d_in[6];
    const float* emb  = (const float*)d_in[8];
    const float* WM   = (const float*)d_in[9];
    const float* WW   = (const float*)d_in[10];
    const float* bW   = (const float*)d_in[11];

    unsigned short* emb16 = (unsigned short*)d_ws;                   // 20 MB
    unsigned int* WMP = (unsigned int*)(emb16 + (size_t)VOCAB * DD); // 80 KB
    unsigned int* WWP = WMP + NWM;                                   // 12.8 KB
    unsigned int* V16 = WWP + NWW;                                   // 12 MB
    float* PT = (float*)(V16 + (size_t)RR * (DD / 2));               // 3.84 MB
    float* EW = PT + (size_t)RR * AA;                                // 6.4 MB
    float* out = (float*)d_out;                                      // [2, B, A]

    const int nnz = in_sizes[4];

    hipMemsetAsync(d_out, 0, (size_t)out_size * sizeof(float), stream);

    prep_kernel<<<(NC4 + NWM + NWW + 255) / 256, 256, 0, stream>>>(
        emb, WM, WW, emb16, WMP, WWP);
    ew_gemm_kernel<<<(VOCAB + 31) / 32, 256, 0, stream>>>(emb16, WWP, EW);
    v_gemm_kernel<<<(RR + 31) / 32, 256, 0, stream>>>(ypos, WMP, V16);
    attn_kernel<<<RR, 256, 0, stream>>>(hist, emb16, V16, EW, bW, PT);

    const int gpm = (nnz + 3) >> 2;
    const int spmm_blocks = (2 * gpm * 32 + 255) / 256;
    spmm_kernel<<<spmm_blocks, 256, 0, stream>>>(uidx, uval, iidx, ival, PT, out, nnz);
}

// Round 17
// 225.869 us; speedup vs baseline: 1.1398x; 1.1099x over previous
//
#include <hip/hip_runtime.h>
#include <math.h>

#define VOCAB 50000
#define DD 200
#define AA 32
#define RR 30000
#define LL 40
#define BB 10000
#define NPRIV 4                  /* privatized output copies */

typedef _Float16 half2_t __attribute__((ext_vector_type(2)));

static __device__ __forceinline__ unsigned short f2h(float f) {
    return __builtin_bit_cast(unsigned short, (_Float16)f);   // RNE
}
static __device__ __forceinline__ float hlo(unsigned int u) {
    return (float)__builtin_bit_cast(_Float16, (unsigned short)(u & 0xFFFFu));
}
static __device__ __forceinline__ float hhi(unsigned int u) {
    return (float)__builtin_bit_cast(_Float16, (unsigned short)(u >> 16));
}
static __device__ __forceinline__ unsigned int pkh(float lo, float hi) {
    return (unsigned int)f2h(lo) | ((unsigned int)f2h(hi) << 16);
}
// packed f16 dot2: acc += a.lo*b.lo + a.hi*b.hi
static __device__ __forceinline__ float dot2(unsigned int a, unsigned int b, float acc) {
#if __has_builtin(__builtin_amdgcn_fdot2)
    return __builtin_amdgcn_fdot2(__builtin_bit_cast(half2_t, a),
                                  __builtin_bit_cast(half2_t, b), acc, false);
#else
    return acc + hlo(a) * hlo(b) + hhi(a) * hhi(b);
#endif
}

// ---------------------------------------------------------------------------
// Kernel 0: prep — emb f32->f16 cvt + WM/WW pair-packing, one launch.
// ---------------------------------------------------------------------------
#define NC4 (VOCAB * DD / 4)     /* 2,500,000 float4 chunks */
#define NWM ((DD / 2) * DD)      /* 20,000 */
#define NWW (AA * (DD / 2))      /* 3,200 */
__global__ __launch_bounds__(256) void prep_kernel(
    const float* __restrict__ emb, const float* __restrict__ WM,
    const float* __restrict__ WW, unsigned short* __restrict__ emb16,
    unsigned int* __restrict__ WMP, unsigned int* __restrict__ WWP)
{
    int i = blockIdx.x * 256 + threadIdx.x;
    if (i < NC4) {
        float4 f = ((const float4*)emb)[i];
        ushort4 u;
        u.x = f2h(f.x); u.y = f2h(f.y); u.z = f2h(f.z); u.w = f2h(f.w);
        ((ushort4*)emb16)[i] = u;
    } else if (i < NC4 + NWM) {
        int k = i - NC4;
        int e2 = k / DD, d = k - e2 * DD;
        WMP[k] = pkh(WM[(2 * e2) * DD + d], WM[(2 * e2 + 1) * DD + d]);
    } else if (i < NC4 + NWM + NWW) {
        int k = i - NC4 - NWM;
        int a = k / (DD / 2), c = k - a * (DD / 2);
        WWP[k] = pkh(WW[a * DD + 2 * c], WW[a * DD + 2 * c + 1]);
    }
}

// ---------------------------------------------------------------------------
// Kernel 1: V = Y @ W_M  with f16 dot2. Y staged as packed f16 in LDS
// (cvt on the fly). Output packed f16 pairs V16[r][i] = (d=2i, d=2i+1).
// ---------------------------------------------------------------------------
__global__ __launch_bounds__(256) void v_gemm_kernel(
    const float* __restrict__ Y, const unsigned int* __restrict__ WMP,
    unsigned int* __restrict__ V16)
{
    __shared__ unsigned int yt[32 * (DD / 2)];   // 12.8 KB packed f16
    const int r0 = blockIdx.x * 32;
    const int tid = threadIdx.x;

    for (int i = tid; i < 32 * 50; i += 256) {   // 50 float4 chunks per row
        int j = i / 50, c = i - 50 * j;
        int r = r0 + j;
        float4 f = (r < RR) ? ((const float4*)(Y + (size_t)r * DD))[c]
                            : make_float4(0.f, 0.f, 0.f, 0.f);
        uint2 u = make_uint2(pkh(f.x, f.y), pkh(f.z, f.w));
        ((uint2*)yt)[i] = u;
    }
    __syncthreads();

    if (tid < DD) {
        float acc[32];
        #pragma unroll
        for (int j = 0; j < 32; ++j) acc[j] = 0.f;
        for (int e2 = 0; e2 < DD / 2; e2 += 2) {
            unsigned int w0 = WMP[e2 * DD + tid];        // coalesced
            unsigned int w1 = WMP[(e2 + 1) * DD + tid];
            #pragma unroll
            for (int j = 0; j < 32; ++j) {
                uint2 y2 = *(const uint2*)(yt + j * (DD / 2) + e2); // broadcast b64
                acc[j] = dot2(y2.x, w0, acc[j]);
                acc[j] = dot2(y2.y, w1, acc[j]);
            }
        }
        #pragma unroll
        for (int j = 0; j < 32; ++j) {
            float partner = __shfl_xor(acc[j], 1);
            int r = r0 + j;
            if (r < RR && (tid & 1) == 0)
                V16[(size_t)r * (DD / 2) + (tid >> 1)] =
                    pkh(acc[j], partner);
        }
    }
}

// ---------------------------------------------------------------------------
// Kernel 2: per-review attention -> p_t [R, A].  Exact R11/R13 form
// (measured 98.5 us, no spill): LDS-staged e_w + fused dx->wgt->z in f32,
// wgt = exp(dx-8) shift-invariant; separate zss/sws/zsp arrays; f16-dot2
// projection against WWP. (EW-decomposition, pk_fma, LDS-overlay all
// measured dead: R12/R14/R15/R16.)
// ---------------------------------------------------------------------------
__global__ __launch_bounds__(256, 8) void attn_kernel(
    const int* __restrict__ hist, const unsigned short* __restrict__ emb16,
    const unsigned int* __restrict__ V16, const unsigned int* __restrict__ WWP,
    const float* __restrict__ bW, float* __restrict__ PT)
{
    __shared__ __align__(16) unsigned short ew[LL * DD];  // 16000 B (f16)
    __shared__ __align__(16) unsigned int vp[DD / 2];     // 400 B packed f16
    __shared__ float zss[4][DD];                          // 3200 B
    __shared__ float sws[4];
    __shared__ __align__(16) unsigned int zsp[DD / 2];    // 400 B packed z

    const int r = blockIdx.x;
    const int tid = threadIdx.x;
    const int* hrow = hist + r * LL;

    // ---- staging: all loads issued up-front -------------------------------
    const int i0 = tid, i1 = tid + 256, i2 = tid + 512, i3 = tid + 768;
    const int l0 = i0 / 25, c0 = i0 - 25 * l0;
    const int l1 = i1 / 25, c1 = i1 - 25 * l1;
    const int l2 = i2 / 25, c2 = i2 - 25 * l2;
    const int l3 = i3 / 25, c3 = i3 - 25 * l3;
    const bool has3 = (i3 < LL * 25);

    int w0 = hrow[l0];
    int w1 = hrow[l1];
    int w2 = hrow[l2];
    int w3 = has3 ? hrow[l3] : 0;

    uint4 q0 = ((const uint4*)(emb16 + (size_t)w0 * DD))[c0];
    uint4 q1 = ((const uint4*)(emb16 + (size_t)w1 * DD))[c1];
    uint4 q2 = ((const uint4*)(emb16 + (size_t)w2 * DD))[c2];
    uint4 q3 = has3 ? ((const uint4*)(emb16 + (size_t)w3 * DD))[c3]
                    : make_uint4(0u, 0u, 0u, 0u);
    uint4 vv = make_uint4(0u, 0u, 0u, 0u);
    if (tid < 25) vv = ((const uint4*)(V16 + (size_t)r * (DD / 2)))[tid];

    ((uint4*)ew)[i0] = q0;
    ((uint4*)ew)[i1] = q1;
    ((uint4*)ew)[i2] = q2;
    if (has3) ((uint4*)ew)[i3] = q3;
    if (tid < 25) ((uint4*)vp)[tid] = vv;
    __syncthreads();

    const int wave = tid >> 6, lane = tid & 63;
    const int half = lane >> 5, s = lane & 31;
    const bool act = (s < 25);

    // hoist this lane's v chunk (dims 8s..8s+7) into registers
    uint4 vq = act ? ((const uint4*)vp)[s] : make_uint4(0u, 0u, 0u, 0u);

    // fused dx -> wgt -> z over this wave's 10 words (2 per iteration)
    float z0 = 0.f, z1 = 0.f, z2 = 0.f, z3 = 0.f,
          z4 = 0.f, z5 = 0.f, z6 = 0.f, z7 = 0.f;
    float sw = 0.f;
    #pragma unroll 1
    for (int j = 0; j < 5; ++j) {
        const int l = wave * 10 + 2 * j + half;
        float p = 0.f;
        uint4 eq = make_uint4(0u, 0u, 0u, 0u);
        if (act) {
            eq = *(const uint4*)(ew + l * DD + s * 8);
            p = dot2(eq.x, vq.x, p);
            p = dot2(eq.y, vq.y, p);
            p = dot2(eq.z, vq.z, p);
            p = dot2(eq.w, vq.w, p);
        }
        #pragma unroll
        for (int off = 16; off; off >>= 1) p += __shfl_xor(p, off);
        float wgt = __expf(p - 8.0f);   // shift-invariant unnormalized weight
        sw += wgt;
        z0 += wgt * hlo(eq.x); z1 += wgt * hhi(eq.x);
        z2 += wgt * hlo(eq.y); z3 += wgt * hhi(eq.y);
        z4 += wgt * hlo(eq.z); z5 += wgt * hhi(eq.z);
        z6 += wgt * hlo(eq.w); z7 += wgt * hhi(eq.w);
    }

    // combine the two halves (word 2j+0 and 2j+1 live in half 0/1)
    z0 += __shfl_xor(z0, 32); z1 += __shfl_xor(z1, 32);
    z2 += __shfl_xor(z2, 32); z3 += __shfl_xor(z3, 32);
    z4 += __shfl_xor(z4, 32); z5 += __shfl_xor(z5, 32);
    z6 += __shfl_xor(z6, 32); z7 += __shfl_xor(z7, 32);
    float swt = sw + __shfl_xor(sw, 32);   // this wave's 10-word weight sum
    if (half == 0 && act) {
        ((float4*)zss[wave])[2 * s]     = make_float4(z0, z1, z2, z3);
        ((float4*)zss[wave])[2 * s + 1] = make_float4(z4, z5, z6, z7);
    }
    if (lane == 0) sws[wave] = swt;
    __syncthreads();

    // combine wave partials, normalize, pack to f16 pairs
    if (tid < DD / 2) {
        float tot = sws[0] + sws[1] + sws[2] + sws[3];
        int d = 2 * tid;
        float za = (zss[0][d]     + zss[1][d]     + zss[2][d]     + zss[3][d])     / tot;
        float zb = (zss[0][d + 1] + zss[1][d + 1] + zss[2][d + 1] + zss[3][d + 1]) / tot;
        zsp[tid] = pkh(za, zb);
    }
    __syncthreads();

    // p_t[r][a] = z_s . W_W[a] + b_W[a]   (8 threads per aspect, dot2)
    {
        int a = tid >> 3, j = tid & 7;
        float acc = 0.f;
        #pragma unroll
        for (int k = 0; k < 13; ++k) {
            int c = j + 8 * k;
            if (c < DD / 2) acc = dot2(zsp[c], WWP[a * (DD / 2) + c], acc);
        }
        #pragma unroll
        for (int off = 4; off; off >>= 1) acc += __shfl_xor(acc, off);
        if (j == 0) PT[r * AA + a] = acc + bW[a];
    }
}

// ---------------------------------------------------------------------------
// Kernel 3: both sparse [B,R] @ p_t [R,A] in one launch, atomics into
// NPRIV privatized output copies (copy = grp & (NPRIV-1)) to cut
// same-address serialization ~4x. 32 lanes per group of 4 nnz.
// ---------------------------------------------------------------------------
__global__ __launch_bounds__(256) void spmm_kernel(
    const int* __restrict__ uidx, const float* __restrict__ uval,
    const int* __restrict__ iidx, const float* __restrict__ ival,
    const float* __restrict__ PT, float* __restrict__ outP, int nnz)
{
    int g = blockIdx.x * 256 + threadIdx.x;
    int grp = g >> 5;
    int a = g & 31;
    const int gpm = (nnz + 3) >> 2;       // 4-nnz groups per matrix
    const int* idx = uidx;
    const float* val = uval;
    size_t obase = 0;
    if (grp >= gpm) {                     // second matrix
        grp -= gpm;
        if (grp >= gpm) return;
        idx = iidx; val = ival; obase = (size_t)BB * AA;
    }
    float* o = outP + (size_t)(grp & (NPRIV - 1)) * (2 * BB * AA) + obase;
    const int n0 = grp * 4;

    if (n0 + 4 <= nnz) {
        int4   rows = *(const int4*)(idx + n0);
        int4   cols = *(const int4*)(idx + nnz + n0);
        float4 ws   = *(const float4*)(val + n0);
        atomicAdd(&o[rows.x * AA + a], ws.x * PT[cols.x * AA + a]);
        atomicAdd(&o[rows.y * AA + a], ws.y * PT[cols.y * AA + a]);
        atomicAdd(&o[rows.z * AA + a], ws.z * PT[cols.z * AA + a]);
        atomicAdd(&o[rows.w * AA + a], ws.w * PT[cols.w * AA + a]);
    } else {
        for (int k = 0; k < 4; ++k) {
            int n = n0 + k;
            if (n >= nnz) break;
            int row = idx[n];
            int col = idx[nnz + n];
            float w = val[n];
            atomicAdd(&o[row * AA + a], w * PT[col * AA + a]);
        }
    }
}

// ---------------------------------------------------------------------------
// Kernel 4: reduce NPRIV copies -> d_out (fully writes output, no memset).
// ---------------------------------------------------------------------------
__global__ __launch_bounds__(256) void reduce_kernel(
    const float* __restrict__ outP, float* __restrict__ out)
{
    const int N4 = 2 * BB * AA / 4;
    int i = blockIdx.x * 256 + threadIdx.x;
    if (i >= N4) return;
    float4 s = ((const float4*)outP)[i];
    #pragma unroll
    for (int k = 1; k < NPRIV; ++k) {
        float4 t = ((const float4*)(outP + (size_t)k * 2 * BB * AA))[i];
        s.x += t.x; s.y += t.y; s.z += t.z; s.w += t.w;
    }
    ((float4*)out)[i] = s;
}

extern "C" void kernel_launch(void* const* d_in, const int* in_sizes, int n_in,
                              void* d_out, int out_size, void* d_ws, size_t ws_size,
                              hipStream_t stream) {
    const int*   hist = (const int*)d_in[0];
    const float* ypos = (const float*)d_in[1];
    const int*   uidx = (const int*)d_in[3];
    const float* uval = (const float*)d_in[4];
    const int*   iidx = (const int*)d_in[5];
    const float* ival = (const float*)d_in[6];
    const float* emb  = (const float*)d_in[8];
    const float* WM   = (const float*)d_in[9];
    const float* WW   = (const float*)d_in[10];
    const float* bW   = (const float*)d_in[11];

    unsigned short* emb16 = (unsigned short*)d_ws;                   // 20 MB
    unsigned int* WMP = (unsigned int*)(emb16 + (size_t)VOCAB * DD); // 80 KB
    unsigned int* WWP = WMP + NWM;                                   // 12.8 KB
    unsigned int* V16 = WWP + NWW;                                   // 12 MB
    float* PT = (float*)(V16 + (size_t)RR * (DD / 2));               // 3.84 MB
    float* outP = PT + (size_t)RR * AA;                              // 10.24 MB
    float* out = (float*)d_out;                                      // [2, B, A]

    const int nnz = in_sizes[4];

    hipMemsetAsync(outP, 0, (size_t)NPRIV * 2 * BB * AA * sizeof(float), stream);

    prep_kernel<<<(NC4 + NWM + NWW + 255) / 256, 256, 0, stream>>>(
        emb, WM, WW, emb16, WMP, WWP);
    v_gemm_kernel<<<(RR + 31) / 32, 256, 0, stream>>>(ypos, WMP, V16);
    attn_kernel<<<RR, 256, 0, stream>>>(hist, emb16, V16, WWP, bW, PT);

    const int gpm = (nnz + 3) >> 2;
    const int spmm_blocks = (2 * gpm * 32 + 255) / 256;
    spmm_kernel<<<spmm_blocks, 256, 0, stream>>>(uidx, uval, iidx, ival, PT, outP, nnz);
    reduce_kernel<<<(2 * BB * AA / 4 + 255) / 256, 256, 0, stream>>>(outP, out);
}

// Round 18
// 220.362 us; speedup vs baseline: 1.1683x; 1.0250x over previous
//
#include <hip/hip_runtime.h>
#include <math.h>

#define VOCAB 50000
#define DD 200
#define AA 32
#define RR 30000
#define LL 40
#define BB 10000

typedef _Float16 half2_t __attribute__((ext_vector_type(2)));

static __device__ __forceinline__ unsigned short f2h(float f) {
    return __builtin_bit_cast(unsigned short, (_Float16)f);   // RNE
}
static __device__ __forceinline__ float hlo(unsigned int u) {
    return (float)__builtin_bit_cast(_Float16, (unsigned short)(u & 0xFFFFu));
}
static __device__ __forceinline__ float hhi(unsigned int u) {
    return (float)__builtin_bit_cast(_Float16, (unsigned short)(u >> 16));
}
static __device__ __forceinline__ unsigned int pkh(float lo, float hi) {
    return (unsigned int)f2h(lo) | ((unsigned int)f2h(hi) << 16);
}
// packed f16 dot2: acc += a.lo*b.lo + a.hi*b.hi
static __device__ __forceinline__ float dot2(unsigned int a, unsigned int b, float acc) {
#if __has_builtin(__builtin_amdgcn_fdot2)
    return __builtin_amdgcn_fdot2(__builtin_bit_cast(half2_t, a),
                                  __builtin_bit_cast(half2_t, b), acc, false);
#else
    return acc + hlo(a) * hlo(b) + hhi(a) * hhi(b);
#endif
}

// ---------------------------------------------------------------------------
// Kernel 0: prep — emb f32->f16 cvt + WM/WW pair-packing, one launch.
// ---------------------------------------------------------------------------
#define NC4 (VOCAB * DD / 4)     /* 2,500,000 float4 chunks */
#define NWM ((DD / 2) * DD)      /* 20,000 */
#define NWW (AA * (DD / 2))      /* 3,200 */
__global__ __launch_bounds__(256) void prep_kernel(
    const float* __restrict__ emb, const float* __restrict__ WM,
    const float* __restrict__ WW, unsigned short* __restrict__ emb16,
    unsigned int* __restrict__ WMP, unsigned int* __restrict__ WWP)
{
    int i = blockIdx.x * 256 + threadIdx.x;
    if (i < NC4) {
        float4 f = ((const float4*)emb)[i];
        ushort4 u;
        u.x = f2h(f.x); u.y = f2h(f.y); u.z = f2h(f.z); u.w = f2h(f.w);
        ((ushort4*)emb16)[i] = u;
    } else if (i < NC4 + NWM) {
        int k = i - NC4;
        int e2 = k / DD, d = k - e2 * DD;
        WMP[k] = pkh(WM[(2 * e2) * DD + d], WM[(2 * e2 + 1) * DD + d]);
    } else if (i < NC4 + NWM + NWW) {
        int k = i - NC4 - NWM;
        int a = k / (DD / 2), c = k - a * (DD / 2);
        WWP[k] = pkh(WW[a * DD + 2 * c], WW[a * DD + 2 * c + 1]);
    }
}

// ---------------------------------------------------------------------------
// Kernel 1: V = Y @ W_M  with f16 dot2. Y staged as packed f16 in LDS
// (cvt on the fly). Output packed f16 pairs V16[r][i] = (d=2i, d=2i+1).
// ---------------------------------------------------------------------------
__global__ __launch_bounds__(256) void v_gemm_kernel(
    const float* __restrict__ Y, const unsigned int* __restrict__ WMP,
    unsigned int* __restrict__ V16)
{
    __shared__ unsigned int yt[32 * (DD / 2)];   // 12.8 KB packed f16
    const int r0 = blockIdx.x * 32;
    const int tid = threadIdx.x;

    for (int i = tid; i < 32 * 50; i += 256) {   // 50 float4 chunks per row
        int j = i / 50, c = i - 50 * j;
        int r = r0 + j;
        float4 f = (r < RR) ? ((const float4*)(Y + (size_t)r * DD))[c]
                            : make_float4(0.f, 0.f, 0.f, 0.f);
        uint2 u = make_uint2(pkh(f.x, f.y), pkh(f.z, f.w));
        ((uint2*)yt)[i] = u;
    }
    __syncthreads();

    if (tid < DD) {
        float acc[32];
        #pragma unroll
        for (int j = 0; j < 32; ++j) acc[j] = 0.f;
        for (int e2 = 0; e2 < DD / 2; e2 += 2) {
            unsigned int w0 = WMP[e2 * DD + tid];        // coalesced
            unsigned int w1 = WMP[(e2 + 1) * DD + tid];
            #pragma unroll
            for (int j = 0; j < 32; ++j) {
                uint2 y2 = *(const uint2*)(yt + j * (DD / 2) + e2); // broadcast b64
                acc[j] = dot2(y2.x, w0, acc[j]);
                acc[j] = dot2(y2.y, w1, acc[j]);
            }
        }
        #pragma unroll
        for (int j = 0; j < 32; ++j) {
            float partner = __shfl_xor(acc[j], 1);
            int r = r0 + j;
            if (r < RR && (tid & 1) == 0)
                V16[(size_t)r * (DD / 2) + (tid >> 1)] =
                    pkh(acc[j], partner);
        }
    }
}

// ---------------------------------------------------------------------------
// Kernel 2: per-review attention -> p_t [R, A].  R11/R13 structure with the
// j-loop FULLY UNROLLED: eq comes from LDS (not global), and R5 proved
// unrolled LDS reads don't trigger the gather-hoist spill (VGPR 12 there).
// unroll 1 serialized the ~30cy ds_read->dot2->butterfly->exp chain 5x;
// unrolling lets the scheduler interleave the 5 independent chains.
// ---------------------------------------------------------------------------
__global__ __launch_bounds__(256, 8) void attn_kernel(
    const int* __restrict__ hist, const unsigned short* __restrict__ emb16,
    const unsigned int* __restrict__ V16, const unsigned int* __restrict__ WWP,
    const float* __restrict__ bW, float* __restrict__ PT)
{
    __shared__ __align__(16) unsigned short ew[LL * DD];  // 16000 B (f16)
    __shared__ __align__(16) unsigned int vp[DD / 2];     // 400 B packed f16
    __shared__ float zss[4][DD];                          // 3200 B
    __shared__ float sws[4];
    __shared__ __align__(16) unsigned int zsp[DD / 2];    // 400 B packed z

    const int r = blockIdx.x;
    const int tid = threadIdx.x;
    const int* hrow = hist + r * LL;

    // ---- staging: all loads issued up-front -------------------------------
    const int i0 = tid, i1 = tid + 256, i2 = tid + 512, i3 = tid + 768;
    const int l0 = i0 / 25, c0 = i0 - 25 * l0;
    const int l1 = i1 / 25, c1 = i1 - 25 * l1;
    const int l2 = i2 / 25, c2 = i2 - 25 * l2;
    const int l3 = i3 / 25, c3 = i3 - 25 * l3;
    const bool has3 = (i3 < LL * 25);

    int w0 = hrow[l0];
    int w1 = hrow[l1];
    int w2 = hrow[l2];
    int w3 = has3 ? hrow[l3] : 0;

    uint4 q0 = ((const uint4*)(emb16 + (size_t)w0 * DD))[c0];
    uint4 q1 = ((const uint4*)(emb16 + (size_t)w1 * DD))[c1];
    uint4 q2 = ((const uint4*)(emb16 + (size_t)w2 * DD))[c2];
    uint4 q3 = has3 ? ((const uint4*)(emb16 + (size_t)w3 * DD))[c3]
                    : make_uint4(0u, 0u, 0u, 0u);
    uint4 vv = make_uint4(0u, 0u, 0u, 0u);
    if (tid < 25) vv = ((const uint4*)(V16 + (size_t)r * (DD / 2)))[tid];

    ((uint4*)ew)[i0] = q0;
    ((uint4*)ew)[i1] = q1;
    ((uint4*)ew)[i2] = q2;
    if (has3) ((uint4*)ew)[i3] = q3;
    if (tid < 25) ((uint4*)vp)[tid] = vv;
    __syncthreads();

    const int wave = tid >> 6, lane = tid & 63;
    const int half = lane >> 5, s = lane & 31;
    const bool act = (s < 25);

    // hoist this lane's v chunk (dims 8s..8s+7) into registers
    uint4 vq = act ? ((const uint4*)vp)[s] : make_uint4(0u, 0u, 0u, 0u);

    // fused dx -> wgt -> z over this wave's 10 words (2 per iteration)
    float z0 = 0.f, z1 = 0.f, z2 = 0.f, z3 = 0.f,
          z4 = 0.f, z5 = 0.f, z6 = 0.f, z7 = 0.f;
    float sw = 0.f;
    #pragma unroll
    for (int j = 0; j < 5; ++j) {
        const int l = wave * 10 + 2 * j + half;
        float p = 0.f;
        uint4 eq = make_uint4(0u, 0u, 0u, 0u);
        if (act) {
            eq = *(const uint4*)(ew + l * DD + s * 8);
            p = dot2(eq.x, vq.x, p);
            p = dot2(eq.y, vq.y, p);
            p = dot2(eq.z, vq.z, p);
            p = dot2(eq.w, vq.w, p);
        }
        #pragma unroll
        for (int off = 16; off; off >>= 1) p += __shfl_xor(p, off);
        float wgt = __expf(p - 8.0f);   // shift-invariant unnormalized weight
        sw += wgt;
        z0 += wgt * hlo(eq.x); z1 += wgt * hhi(eq.x);
        z2 += wgt * hlo(eq.y); z3 += wgt * hhi(eq.y);
        z4 += wgt * hlo(eq.z); z5 += wgt * hhi(eq.z);
        z6 += wgt * hlo(eq.w); z7 += wgt * hhi(eq.w);
    }

    // combine the two halves (word 2j+0 and 2j+1 live in half 0/1)
    z0 += __shfl_xor(z0, 32); z1 += __shfl_xor(z1, 32);
    z2 += __shfl_xor(z2, 32); z3 += __shfl_xor(z3, 32);
    z4 += __shfl_xor(z4, 32); z5 += __shfl_xor(z5, 32);
    z6 += __shfl_xor(z6, 32); z7 += __shfl_xor(z7, 32);
    float swt = sw + __shfl_xor(sw, 32);   // this wave's 10-word weight sum
    if (half == 0 && act) {
        ((float4*)zss[wave])[2 * s]     = make_float4(z0, z1, z2, z3);
        ((float4*)zss[wave])[2 * s + 1] = make_float4(z4, z5, z6, z7);
    }
    if (lane == 0) sws[wave] = swt;
    __syncthreads();

    // combine wave partials, normalize, pack to f16 pairs
    if (tid < DD / 2) {
        float tot = sws[0] + sws[1] + sws[2] + sws[3];
        int d = 2 * tid;
        float za = (zss[0][d]     + zss[1][d]     + zss[2][d]     + zss[3][d])     / tot;
        float zb = (zss[0][d + 1] + zss[1][d + 1] + zss[2][d + 1] + zss[3][d + 1]) / tot;
        zsp[tid] = pkh(za, zb);
    }
    __syncthreads();

    // p_t[r][a] = z_s . W_W[a] + b_W[a]   (8 threads per aspect, dot2)
    {
        int a = tid >> 3, j = tid & 7;
        float acc = 0.f;
        #pragma unroll
        for (int k = 0; k < 13; ++k) {
            int c = j + 8 * k;
            if (c < DD / 2) acc = dot2(zsp[c], WWP[a * (DD / 2) + c], acc);
        }
        #pragma unroll
        for (int off = 4; off; off >>= 1) acc += __shfl_xor(acc, off);
        if (j == 0) PT[r * AA + a] = acc + bW[a];
    }
}

// ---------------------------------------------------------------------------
// Kernel 3: both sparse [B,R] @ p_t [R,A] in one launch.
// 32 lanes per GROUP OF 4 nnz, single output copy (privatization measured
// neutral in R17 -> atomics are throughput-bound, keep it simple).
// ---------------------------------------------------------------------------
__global__ __launch_bounds__(256) void spmm_kernel(
    const int* __restrict__ uidx, const float* __restrict__ uval,
    const int* __restrict__ iidx, const float* __restrict__ ival,
    const float* __restrict__ PT, float* __restrict__ out, int nnz)
{
    int g = blockIdx.x * 256 + threadIdx.x;
    int grp = g >> 5;
    int a = g & 31;
    const int gpm = (nnz + 3) >> 2;       // 4-nnz groups per matrix
    const int* idx = uidx;
    const float* val = uval;
    float* o = out;
    if (grp >= gpm) {                     // second matrix
        grp -= gpm;
        if (grp >= gpm) return;
        idx = iidx; val = ival; o += BB * AA;
    }
    const int n0 = grp * 4;

    if (n0 + 4 <= nnz) {
        int4   rows = *(const int4*)(idx + n0);
        int4   cols = *(const int4*)(idx + nnz + n0);
        float4 ws   = *(const float4*)(val + n0);
        atomicAdd(&o[rows.x * AA + a], ws.x * PT[cols.x * AA + a]);
        atomicAdd(&o[rows.y * AA + a], ws.y * PT[cols.y * AA + a]);
        atomicAdd(&o[rows.z * AA + a], ws.z * PT[cols.z * AA + a]);
        atomicAdd(&o[rows.w * AA + a], ws.w * PT[cols.w * AA + a]);
    } else {
        for (int k = 0; k < 4; ++k) {
            int n = n0 + k;
            if (n >= nnz) break;
            int row = idx[n];
            int col = idx[nnz + n];
            float w = val[n];
            atomicAdd(&o[row * AA + a], w * PT[col * AA + a]);
        }
    }
}

extern "C" void kernel_launch(void* const* d_in, const int* in_sizes, int n_in,
                              void* d_out, int out_size, void* d_ws, size_t ws_size,
                              hipStream_t stream) {
    const int*   hist = (const int*)d_in[0];
    const float* ypos = (const float*)d_in[1];
    const int*   uidx = (const int*)d_in[3];
    const float* uval = (const float*)d_in[4];
    const int*   iidx = (const int*)d_in[5];
    const float* ival = (const float*)d_in[6];
    const float* emb  = (const float*)d_in[8];
    const float* WM   = (const float*)d_in[9];
    const float* WW   = (const float*)d_in[10];
    const float* bW   = (const float*)d_in[11];

    unsigned short* emb16 = (unsigned short*)d_ws;                   // 20 MB
    unsigned int* WMP = (unsigned int*)(emb16 + (size_t)VOCAB * DD); // 80 KB
    unsigned int* WWP = WMP + NWM;                                   // 12.8 KB
    unsigned int* V16 = WWP + NWW;                                   // 12 MB
    float* PT = (float*)(V16 + (size_t)RR * (DD / 2));               // 3.84 MB
    float* out = (float*)d_out;                                      // [2, B, A]

    const int nnz = in_sizes[4];

    hipMemsetAsync(d_out, 0, (size_t)out_size * sizeof(float), stream);

    prep_kernel<<<(NC4 + NWM + NWW + 255) / 256, 256, 0, stream>>>(
        emb, WM, WW, emb16, WMP, WWP);
    v_gemm_kernel<<<(RR + 31) / 32, 256, 0, stream>>>(ypos, WMP, V16);
    attn_kernel<<<RR, 256, 0, stream>>>(hist, emb16, V16, WWP, bW, PT);

    const int gpm = (nnz + 3) >> 2;
    const int spmm_blocks = (2 * gpm * 32 + 255) / 256;
    spmm_kernel<<<spmm_blocks, 256, 0, stream>>>(uidx, uval, iidx, ival, PT, out, nnz);
}